// Round 3
// baseline (1211.713 us; speedup 1.0000x reference)
//
#include <hip/hip_runtime.h>
#include <math.h>

#define GG 512
#define TT 25
#define PP 10
#define MM 5
#define EE 32
#define HID 32
#define HH 128
#define NEDGE 40
#define NGRAPH (GG*TT)          // 12800
#define NTOT (GG*TT*PP)         // 128000

#define KCOMB 196               // 66 (x|add) + 128 (h) + 2 pad
#define CHUNK 28                // ks per LDS chunk (7 chunks)
#define NCH 7
#define WBUF_F (CHUNK*512)      // 14336 floats = 56 KiB per chunk buffer
#define SX_STRIDE 200           // padded row stride for activation vector

// ---------------------------------------------------------------------------
// Prep: build combined weight tensor wcomb[t][k][j][gate] (float4 per (k,j)),
// k<66 -> W_ih col k; 66<=k<194 -> W_hh col k-66; k>=194 -> 0.
// Also bsum[t][j][gate] = b_ih + b_hh.
// ---------------------------------------------------------------------------
__global__ void prep_kernel(const float* __restrict__ W_ih, const float* __restrict__ W_hh,
                            const float* __restrict__ b_ih, const float* __restrict__ b_hh,
                            float* __restrict__ wcomb, float* __restrict__ bsum)
{
    const int NW = TT*KCOMB*512;   // 2,508,800
    const int NB = TT*512;         // 12,800
    for (int idx = blockIdx.x*blockDim.x + threadIdx.x; idx < NW + NB; idx += gridDim.x*blockDim.x) {
        if (idx < NW) {
            int t = idx / (KCOMB*512); int rem = idx % (KCOMB*512);
            int k = rem / 512; int jc = rem % 512;
            int j = jc >> 2, q = jc & 3;
            float v = 0.f;
            if (k < 66)       v = W_ih[(t*512 + 128*q + j)*66 + k];
            else if (k < 194) v = W_hh[(t*512 + 128*q + j)*128 + (k-66)];
            wcomb[idx] = v;
        } else {
            int i2 = idx - NW;
            int t = i2 / 512; int jc = i2 % 512;
            int j = jc >> 2, q = jc & 3;
            bsum[i2] = b_ih[t*512 + 128*q + j] + b_hh[t*512 + 128*q + j];
        }
    }
}

// ---------------------------------------------------------------------------
// Graph kernel: one 64-thread block per (g,t) vote graph. (unchanged)
// ---------------------------------------------------------------------------
__global__ __launch_bounds__(64) void graph_kernel(
    const float* __restrict__ x0,
    const float* __restrict__ Wb_pos, const float* __restrict__ bb_pos,
    const float* __restrict__ Wb_neg, const float* __restrict__ bb_neg,
    const float* __restrict__ Wd_pos, const float* __restrict__ bd_pos,
    const float* __restrict__ Wd_neg, const float* __restrict__ bd_neg,
    const int* __restrict__ pos_src, const int* __restrict__ pos_dst,
    const int* __restrict__ neg_src, const int* __restrict__ neg_dst,
    float* __restrict__ emb)
{
    __shared__ float Sx[10][64];
    __shared__ float Sm[2][10][64];
    __shared__ float Sagg[6][10][32];
    __shared__ float Sh[2][10][32];
    __shared__ float Shn[2][10][32];
    __shared__ int   Ses[4][40];
    __shared__ int   Scnt[4][10];

    const int gid = blockIdx.x;
    const int nb  = gid * PP;
    const int tid = threadIdx.x;

    for (int i = tid; i < 640; i += 64) ((float*)Sx)[i] = x0[nb*64 + i];
    {
        for (int i = tid; i < 160; i += 64) {
            int b = i / 40, e = i % 40;
            const int* p = (b==0)?pos_src:(b==1)?pos_dst:(b==2)?neg_src:neg_dst;
            ((int*)Ses)[i] = p[gid*40 + e];
        }
    }
    __syncthreads();
    if (tid < 40) {
        int b = tid / 10, n = tid % 10;
        int cc = 0;
        for (int e = 0; e < 40; ++e) cc += (Ses[b][e] == n);
        Scnt[b][n] = cc;
    }
    for (int i = tid; i < 1280; i += 64) ((float*)Sm)[i] = 0.f;
    __syncthreads();
    {
        const int d = tid;
        for (int e = 0; e < 40; ++e) Sm[0][Ses[0][e]][d] += Sx[Ses[1][e]][d];
        for (int e = 0; e < 40; ++e) Sm[1][Ses[2][e]][d] += Sx[Ses[3][e]][d];
    }
    __syncthreads();
    for (int i = tid; i < 1280; i += 64) {
        int s = i / 640, n = (i % 640) / 64;
        ((float*)Sm)[i] /= fmaxf((float)Scnt[s ? 2 : 0][n], 1.f);
    }
    __syncthreads();

    const int sign = tid >> 5;
    const int g4   = (tid >> 3) & 3;
    const int l8   = tid & 7;
    const int c0   = 4*l8;
    const int kp   = g4*8;

    float acc[10][4];
#pragma unroll
    for (int n=0;n<10;++n) { acc[n][0]=0.f; acc[n][1]=0.f; acc[n][2]=0.f; acc[n][3]=0.f; }

    {
        const float* Wb = sign ? Wb_neg : Wb_pos;
        const float* fb0 = sign ? &Sm[1][0][0] : &Sm[0][0][0];
#pragma unroll
        for (int blk = 0; blk < 4; ++blk) {
            const float* bp = ((blk < 2) ? fb0 : &Sx[0][0]) + (blk & 1)*32 + kp;
            const float* wrow = Wb + (blk*32 + kp)*32 + c0;
            for (int kk = 0; kk < 8; ++kk) {
                float4 w = *(const float4*)(wrow + kk*32);
#pragma unroll
                for (int n = 0; n < 10; ++n) {
                    float f = bp[n*64 + kk];
                    acc[n][0] += f*w.x; acc[n][1] += f*w.y;
                    acc[n][2] += f*w.z; acc[n][3] += f*w.w;
                }
            }
        }
    }
#pragma unroll
    for (int n=0;n<10;++n)
#pragma unroll
        for (int q=0;q<4;++q) {
            float v = acc[n][q];
            v += __shfl_xor(v, 8);
            v += __shfl_xor(v, 16);
            acc[n][q] = v;
        }
    {
        const float* bb = sign ? bb_neg : bb_pos;
        float4 b4 = *(const float4*)(bb + c0);
#pragma unroll
        for (int n=0;n<10;++n) {
            acc[n][0]+=b4.x; acc[n][1]+=b4.y; acc[n][2]+=b4.z; acc[n][3]+=b4.w;
            float s = acc[n][0]*acc[n][0]+acc[n][1]*acc[n][1]
                    + acc[n][2]*acc[n][2]+acc[n][3]*acc[n][3];
            s += __shfl_xor(s,1); s += __shfl_xor(s,2); s += __shfl_xor(s,4);
            float rn = 1.f / fmaxf(sqrtf(s), 1e-12f);
            if (g4 == 0) {
                Sh[sign][n][c0+0] = acc[n][0]*rn;
                Sh[sign][n][c0+1] = acc[n][1]*rn;
                Sh[sign][n][c0+2] = acc[n][2]*rn;
                Sh[sign][n][c0+3] = acc[n][3]*rn;
            }
        }
    }
    __syncthreads();

    const int colv = tid & 31;
    for (int l = 0; l < 2; ++l) {
        for (int i = tid; i < 1920; i += 64) ((float*)Sagg)[i] = 0.f;
        __syncthreads();
        {
            const int e0 = 2*sign, e1 = 2*sign + 1;
            const int bA = sign ? 2 : 0;
            const int bC = sign ? 5 : 4;
            for (int e = 0; e < 40; ++e) {
                int sn = Ses[e0][e], dn = Ses[e1][e];
                Sagg[bA][sn][colv] += Sh[sign][dn][colv];
            }
            for (int e = 0; e < 40; ++e) {
                int sn = Ses[e0][e], dn = Ses[e1][e];
                Sagg[bA+1][dn][colv] += Sh[sign][sn][colv];
            }
            for (int e = 0; e < 40; ++e) {
                int sn = Ses[e0][e], dn = Ses[e1][e];
                Sagg[bC][sn][colv] += Sh[1-sign][dn][colv];
            }
        }
        __syncthreads();
        {
            for (int i = tid; i < 1920; i += 64) {
                int b = i / 320, n = (i % 320) / 32;
                int ci = (b==0)?0:(b==1)?1:(b==2)?2:(b==3)?3:(b==4)?0:2;
                ((float*)Sagg)[i] /= fmaxf((float)Scnt[ci][n], 1.f);
            }
        }
        __syncthreads();
#pragma unroll
        for (int n=0;n<10;++n) { acc[n][0]=0.f; acc[n][1]=0.f; acc[n][2]=0.f; acc[n][3]=0.f; }
        {
            const float* ord[7];
            if (sign == 0) {
                ord[0]=&Sagg[0][0][0]; ord[1]=&Sagg[1][0][0]; ord[2]=&Sagg[2][0][0];
                ord[3]=&Sagg[3][0][0]; ord[4]=&Sagg[4][0][0];
                ord[5]=&Sh[0][0][0];   ord[6]=&Sh[1][0][0];
            } else {
                ord[0]=&Sagg[2][0][0]; ord[1]=&Sagg[3][0][0]; ord[2]=&Sagg[0][0][0];
                ord[3]=&Sagg[1][0][0]; ord[4]=&Sagg[5][0][0];
                ord[5]=&Sh[1][0][0];   ord[6]=&Sh[0][0][0];
            }
            const float* Wd = (sign ? Wd_neg : Wd_pos) + l*7168;
            for (int blk = 0; blk < 7; ++blk) {
                const float* bp = ord[blk] + kp;
                const float* wrow = Wd + (blk*32 + kp)*32 + c0;
                for (int kk = 0; kk < 8; ++kk) {
                    float4 w = *(const float4*)(wrow + kk*32);
#pragma unroll
                    for (int n = 0; n < 10; ++n) {
                        float f = bp[n*32 + kk];
                        acc[n][0] += f*w.x; acc[n][1] += f*w.y;
                        acc[n][2] += f*w.z; acc[n][3] += f*w.w;
                    }
                }
            }
        }
#pragma unroll
        for (int n=0;n<10;++n)
#pragma unroll
            for (int q=0;q<4;++q) {
                float v = acc[n][q];
                v += __shfl_xor(v, 8);
                v += __shfl_xor(v, 16);
                acc[n][q] = v;
            }
        {
            const float* bd = (sign ? bd_neg : bd_pos) + l*32;
            float4 b4 = *(const float4*)(bd + c0);
#pragma unroll
            for (int n=0;n<10;++n) {
                acc[n][0]+=b4.x; acc[n][1]+=b4.y; acc[n][2]+=b4.z; acc[n][3]+=b4.w;
                float s = acc[n][0]*acc[n][0]+acc[n][1]*acc[n][1]
                        + acc[n][2]*acc[n][2]+acc[n][3]*acc[n][3];
                s += __shfl_xor(s,1); s += __shfl_xor(s,2); s += __shfl_xor(s,4);
                float rn = 1.f / fmaxf(sqrtf(s), 1e-12f);
                if (g4 == 0) {
                    Shn[sign][n][c0+0]=acc[n][0]*rn; Shn[sign][n][c0+1]=acc[n][1]*rn;
                    Shn[sign][n][c0+2]=acc[n][2]*rn; Shn[sign][n][c0+3]=acc[n][3]*rn;
                }
            }
        }
        __syncthreads();
        for (int i = tid; i < 640; i += 64) ((float*)Sh)[i] = ((float*)Shn)[i];
        __syncthreads();
    }

#pragma unroll
    for (int n = 0; n < 10; ++n) {
        float v = (tid < 32) ? Sh[0][n][tid] : Sh[1][n][tid-32];
        emb[(nb+n)*64 + tid] = v;
    }
}

// ---------------------------------------------------------------------------
// Persistent LSTM with LDS-staged combined weights.
// 256 blocks x 256 threads; block owns 20 rows; thread = (j = tid&127,
// grp = tid>>7) computes rows grp*10..grp*10+9, all 4 gates of hidden j.
// Activation vector av[196] = [emb(64)|add(2)|h(128)|0,0] per row in LDS.
// Weights stream global -> LDS via global_load_lds, double-buffered chunks.
// ---------------------------------------------------------------------------
__device__ __forceinline__ float sigm(float x) { return 1.f/(1.f+expf(-x)); }

__device__ __forceinline__ void stage_chunk(const float* __restrict__ src,
                                            float* dst, int wv, int lane)
{
    // 57344 B chunk; wave wv copies 14 KiB as 14 x (64 lanes x 16 B)
#pragma unroll
    for (int q = 0; q < 14; ++q) {
        const float* g = src + (wv*14 + q)*256 + lane*4;
        float*       l = dst + (wv*14 + q)*256;
        __builtin_amdgcn_global_load_lds(
            (__attribute__((address_space(1))) void*)((unsigned long long)g),
            (__attribute__((address_space(3))) void*)l, 16, 0, 0);
    }
}

__global__ __launch_bounds__(256) void lstm_rec(
    const float* __restrict__ emb, const float* __restrict__ add_info,
    const float* __restrict__ wcomb, const float* __restrict__ bsum,
    const float* __restrict__ hx0, const float* __restrict__ cx0,
    float* __restrict__ hbuf)
{
    extern __shared__ float lds[];
    float* wb0 = lds;                    // 14336 f32
    float* wb1 = lds + WBUF_F;           // 14336 f32
    float* Sx  = lds + 2*WBUF_F;         // 20 rows x SX_STRIDE

    const int tid  = threadIdx.x;
    const int j    = tid & 127;
    const int grp  = tid >> 7;           // 0..1
    const int row0 = blockIdx.x * 20;
    const int r0   = grp * 10;
    const int wv   = tid >> 6;           // wave 0..3
    const int lane = tid & 63;
    const int g0   = 2 * blockIdx.x;

    // init: h -> Sx cols 66..193; pad zeros; emb/add for t=0
    for (int i = tid; i < 20*128; i += 256) {
        int r = i >> 7, k = i & 127;
        Sx[r*SX_STRIDE + 66 + k] = hx0[(row0 + r)*128 + k];
    }
    for (int i = tid; i < 20*6; i += 256) {
        int r = i / 6, k = i % 6;
        Sx[r*SX_STRIDE + 194 + k] = 0.f;
    }
    for (int i = tid; i < 20*64; i += 256) {
        int r = i >> 6, k = i & 63;
        int g = g0 + (r >= 10), p = (r >= 10) ? r - 10 : r;
        Sx[r*SX_STRIDE + k] = emb[((g*TT + 0)*PP + p)*64 + k];
    }
    if (tid < 40) {
        int r = tid >> 1, kk = tid & 1;
        int g = g0 + (r >= 10), p = (r >= 10) ? r - 10 : r;
        Sx[r*SX_STRIDE + 64 + kk] = add_info[((g*MM + 0)*PP + p)*2 + kk];
    }
    float c[10];
#pragma unroll
    for (int r = 0; r < 10; ++r)
        c[r] = cx0[(row0 + r0 + r)*128 + j];

    stage_chunk(wcomb, wb0, wv, lane);   // (t=0, ck=0)
    __syncthreads();                      // drains vmcnt -> chunk 0 ready

    for (int t = 0; t < TT; ++t) {
        float4 bs = ((const float4*)bsum)[t*128 + j];
        float a0[10], a1[10], a2[10], a3[10];
#pragma unroll
        for (int r = 0; r < 10; ++r) { a0[r]=bs.x; a1[r]=bs.y; a2[r]=bs.z; a3[r]=bs.w; }

        const float* wct = wcomb + (size_t)t*KCOMB*512;
        for (int ck = 0; ck < NCH; ++ck) {
            const int par = (t*NCH + ck) & 1;
            float* wcur = par ? wb1 : wb0;
            float* wnxt = par ? wb0 : wb1;
            if (!(t == TT-1 && ck == NCH-1)) {
                const float* nsrc = (ck < NCH-1)
                    ? (wct + (ck+1)*CHUNK*512)
                    : (wcomb + (size_t)(t+1)*KCOMB*512);
                stage_chunk(nsrc, wnxt, wv, lane);
            }
            const float4* wp = (const float4*)wcur;
            const int kbase = ck*CHUNK;
#pragma unroll
            for (int kb = 0; kb < CHUNK/4; ++kb) {
                float4 w0 = wp[(4*kb+0)*128 + j];
                float4 w1 = wp[(4*kb+1)*128 + j];
                float4 w2 = wp[(4*kb+2)*128 + j];
                float4 w3 = wp[(4*kb+3)*128 + j];
#pragma unroll
                for (int r = 0; r < 10; ++r) {
                    float4 f = *(const float4*)&Sx[(r0+r)*SX_STRIDE + kbase + 4*kb];
                    a0[r] += f.x*w0.x + f.y*w1.x + f.z*w2.x + f.w*w3.x;
                    a1[r] += f.x*w0.y + f.y*w1.y + f.z*w2.y + f.w*w3.y;
                    a2[r] += f.x*w0.z + f.y*w1.z + f.z*w2.z + f.w*w3.z;
                    a3[r] += f.x*w0.w + f.y*w1.w + f.z*w2.w + f.w*w3.w;
                }
            }
            __syncthreads();   // next chunk staged AND all reads of wcur done
        }

        // gates + state update + activation refresh for t+1
#pragma unroll
        for (int r = 0; r < 10; ++r) {
            float iv = sigm(a0[r]);
            float fv = sigm(a1[r]);
            float gv = tanhf(a2[r]);
            float ov = sigm(a3[r]);
            float cn = fv*c[r] + iv*gv;
            c[r] = cn;
            float hv = ov*tanhf(cn);
            Sx[(r0+r)*SX_STRIDE + 66 + j] = hv;
            if (t == TT-1) hbuf[(row0 + r0 + r)*128 + j] = hv;
        }
        if (t < TT-1) {
            for (int i = tid; i < 20*64; i += 256) {
                int r = i >> 6, k = i & 63;
                int g = g0 + (r >= 10), p = (r >= 10) ? r - 10 : r;
                Sx[r*SX_STRIDE + k] = emb[((g*TT + (t+1))*PP + p)*64 + k];
            }
            if (tid < 40) {
                int r = tid >> 1, kk = tid & 1;
                int g = g0 + (r >= 10), p = (r >= 10) ? r - 10 : r;
                Sx[r*SX_STRIDE + 64 + kk] = add_info[((g*MM + (t+1)/MM)*PP + p)*2 + kk];
            }
        }
        __syncthreads();   // Sx fully updated before next step's compute
    }
}

// ---------------------------------------------------------------------------
// Final projection: out = h_last @ Wf + bf
// ---------------------------------------------------------------------------
__global__ __launch_bounds__(256) void final_proj(
    const float* __restrict__ hbuf, const float* __restrict__ Wf,
    const float* __restrict__ bf, float* __restrict__ out)
{
    __shared__ float wl[128*32];
    __shared__ float hl[64][128];
    const int tid = threadIdx.x;
    const int row0 = blockIdx.x * 64;
    for (int i = tid; i < 4096; i += 256) wl[i] = Wf[i];
    for (int i = tid; i < 8192; i += 256) hl[i>>7][i&127] = hbuf[row0*128 + i];
    __syncthreads();
    const int e  = tid & 31;
    const int rg = tid >> 5;
    float b = bf[e];
    float acc[8];
#pragma unroll
    for (int r=0;r<8;++r) acc[r] = b;
    for (int k = 0; k < 128; ++k) {
        float w = wl[k*32 + e];
#pragma unroll
        for (int r=0;r<8;++r) acc[r] += hl[rg*8+r][k]*w;
    }
#pragma unroll
    for (int r=0;r<8;++r) out[(row0 + rg*8 + r)*32 + e] = acc[r];
}

// ---------------------------------------------------------------------------
extern "C" void kernel_launch(void* const* d_in, const int* in_sizes, int n_in,
                              void* d_out, int out_size, void* d_ws, size_t ws_size,
                              hipStream_t stream)
{
    const float* x0       = (const float*)d_in[0];
    const float* add_info = (const float*)d_in[1];
    const float* Wb_pos   = (const float*)d_in[2];
    const float* bb_pos   = (const float*)d_in[3];
    const float* Wb_neg   = (const float*)d_in[4];
    const float* bb_neg   = (const float*)d_in[5];
    const float* Wd_pos   = (const float*)d_in[6];
    const float* bd_pos   = (const float*)d_in[7];
    const float* Wd_neg   = (const float*)d_in[8];
    const float* bd_neg   = (const float*)d_in[9];
    const float* W_ih     = (const float*)d_in[10];
    const float* W_hh     = (const float*)d_in[11];
    const float* b_ih     = (const float*)d_in[12];
    const float* b_hh     = (const float*)d_in[13];
    const float* hx0      = (const float*)d_in[14];
    const float* cx0      = (const float*)d_in[15];
    const float* Wf       = (const float*)d_in[16];
    const float* bf       = (const float*)d_in[17];
    const int*   pos_src  = (const int*)d_in[18];
    const int*   pos_dst  = (const int*)d_in[19];
    const int*   neg_src  = (const int*)d_in[20];
    const int*   neg_dst  = (const int*)d_in[21];

    float* ws    = (float*)d_ws;
    float* emb   = ws;                        // 8,192,000 f32
    float* wcomb = emb   + 8192000;           // 2,508,800
    float* bsumw = wcomb + 2508800;           //    12,800
    float* hbuf  = bsumw + 12800;             //   655,360   (total ~45.5 MiB)

    const int ldsBytes = (2*WBUF_F + 20*SX_STRIDE) * 4;   // 130,688 B
    hipFuncSetAttribute((const void*)lstm_rec,
                        hipFuncAttributeMaxDynamicSharedMemorySize, ldsBytes);

    hipLaunchKernelGGL(prep_kernel, dim3(2048), dim3(256), 0, stream,
                       W_ih, W_hh, b_ih, b_hh, wcomb, bsumw);
    hipLaunchKernelGGL(graph_kernel, dim3(NGRAPH), dim3(64), 0, stream,
                       x0, Wb_pos, bb_pos, Wb_neg, bb_neg,
                       Wd_pos, bd_pos, Wd_neg, bd_neg,
                       pos_src, pos_dst, neg_src, neg_dst, emb);
    hipLaunchKernelGGL(lstm_rec, dim3(256), dim3(256), ldsBytes, stream,
                       emb, add_info, wcomb, bsumw, hx0, cx0, hbuf);
    hipLaunchKernelGGL(final_proj, dim3(80), dim3(256), 0, stream,
                       hbuf, Wf, bf, (float*)d_out);
}

// Round 4
// 689.925 us; speedup vs baseline: 1.7563x; 1.7563x over previous
//
#include <hip/hip_runtime.h>
#include <math.h>

#define GG 512
#define TT 25
#define PP 10
#define MM 5
#define EE 32
#define HID 32
#define HH 128
#define NEDGE 40
#define NGRAPH (GG*TT)          // 12800
#define NTOT (GG*TT*PP)         // 128000

typedef __attribute__((ext_vector_type(8))) short short8v;
typedef __attribute__((ext_vector_type(4))) short short4v;
typedef __attribute__((ext_vector_type(4))) float f32x4;

// A-panel LDS index: [s][ki<6][mt<2][lane<64][e<8] (shorts)
#define AIDX(s,ki,mt,l) (((((s)*6+(ki))*2+(mt))*64+(l))*8)
#define WB_PER_T 196608   // 2*6*32*64*8

__device__ __forceinline__ unsigned short f2bf(float x){
    unsigned u = __float_as_uint(x);
    u += 0x7fffu + ((u >> 16) & 1u);
    return (unsigned short)(u >> 16);
}
__device__ __forceinline__ float bf2f(unsigned short s){
    return __uint_as_float(((unsigned)s) << 16);
}
__device__ __forceinline__ float sigm(float x){ return 1.f/(1.f+__expf(-x)); }
__device__ __forceinline__ float tanh_fast(float x){
    float ax = fabsf(x);
    float e  = __expf(-2.f*ax);
    float t  = (1.f-e)/(1.f+e);
    return copysignf(t, x);
}

// ---------------------------------------------------------------------------
// Prep: build MFMA-fragment weight tensor wB[t][s][ki][nt][lane][e] (bf16 bits)
//   k = ki*32 + (lane>>4)*8 + e ; n = nt*16 + (lane&15)
//   k<128 -> W_hh[t][n][k] ; 128<=k<192 -> W_ih[t][n][k-128]
//   s=0: hi bf16, s=1: lo = bf16(w - hi)
// Plus wadd[t][c][n] = W_ih[t][n][64+c]  and bsum[t][n] = b_ih + b_hh.
// ---------------------------------------------------------------------------
__global__ void prep_kernel(const float* __restrict__ W_ih, const float* __restrict__ W_hh,
                            const float* __restrict__ b_ih, const float* __restrict__ b_hh,
                            short* __restrict__ wB, float* __restrict__ wadd,
                            float* __restrict__ bsum)
{
    const int NW = TT*WB_PER_T;          // 4,915,200
    const int NA = TT*2*512;             // 25,600
    const int NB = TT*512;               // 12,800
    for (int idx = blockIdx.x*blockDim.x + threadIdx.x; idx < NW+NA+NB;
         idx += gridDim.x*blockDim.x) {
        if (idx < NW) {
            int e  = idx & 7;
            int l  = (idx >> 3) & 63;
            int nt = (idx >> 9) & 31;
            int rest = idx >> 14;        // (t*2+s)*6 + ki
            int ki = rest % 6; rest /= 6;
            int s  = rest & 1;
            int t  = rest >> 1;
            int k  = ki*32 + (l >> 4)*8 + e;
            int n  = nt*16 + (l & 15);
            float wv = (k < 128) ? W_hh[(size_t)(t*512 + n)*128 + k]
                                 : W_ih[(size_t)(t*512 + n)*66 + (k - 128)];
            unsigned short hi = f2bf(wv);
            unsigned short outv = (s == 0) ? hi : f2bf(wv - bf2f(hi));
            wB[idx] = (short)outv;
        } else if (idx < NW + NA) {
            int i2 = idx - NW;
            int t = i2 / 1024, r = i2 % 1024;
            int cc = r >> 9, n = r & 511;
            wadd[i2] = W_ih[(size_t)(t*512 + n)*66 + 64 + cc];
        } else {
            int i3 = idx - NW - NA;
            bsum[i3] = b_ih[i3] + b_hh[i3];
        }
    }
}

// ---------------------------------------------------------------------------
// Graph kernel: one 64-thread block per (g,t) vote graph. (unchanged)
// ---------------------------------------------------------------------------
__global__ __launch_bounds__(64) void graph_kernel(
    const float* __restrict__ x0,
    const float* __restrict__ Wb_pos, const float* __restrict__ bb_pos,
    const float* __restrict__ Wb_neg, const float* __restrict__ bb_neg,
    const float* __restrict__ Wd_pos, const float* __restrict__ bd_pos,
    const float* __restrict__ Wd_neg, const float* __restrict__ bd_neg,
    const int* __restrict__ pos_src, const int* __restrict__ pos_dst,
    const int* __restrict__ neg_src, const int* __restrict__ neg_dst,
    float* __restrict__ emb)
{
    __shared__ float Sx[10][64];
    __shared__ float Sm[2][10][64];
    __shared__ float Sagg[6][10][32];
    __shared__ float Sh[2][10][32];
    __shared__ float Shn[2][10][32];
    __shared__ int   Ses[4][40];
    __shared__ int   Scnt[4][10];

    const int gid = blockIdx.x;
    const int nb  = gid * PP;
    const int tid = threadIdx.x;

    for (int i = tid; i < 640; i += 64) ((float*)Sx)[i] = x0[nb*64 + i];
    {
        for (int i = tid; i < 160; i += 64) {
            int b = i / 40, e = i % 40;
            const int* p = (b==0)?pos_src:(b==1)?pos_dst:(b==2)?neg_src:neg_dst;
            ((int*)Ses)[i] = p[gid*40 + e];
        }
    }
    __syncthreads();
    if (tid < 40) {
        int b = tid / 10, n = tid % 10;
        int cc = 0;
        for (int e = 0; e < 40; ++e) cc += (Ses[b][e] == n);
        Scnt[b][n] = cc;
    }
    for (int i = tid; i < 1280; i += 64) ((float*)Sm)[i] = 0.f;
    __syncthreads();
    {
        const int d = tid;
        for (int e = 0; e < 40; ++e) Sm[0][Ses[0][e]][d] += Sx[Ses[1][e]][d];
        for (int e = 0; e < 40; ++e) Sm[1][Ses[2][e]][d] += Sx[Ses[3][e]][d];
    }
    __syncthreads();
    for (int i = tid; i < 1280; i += 64) {
        int s = i / 640, n = (i % 640) / 64;
        ((float*)Sm)[i] /= fmaxf((float)Scnt[s ? 2 : 0][n], 1.f);
    }
    __syncthreads();

    const int sign = tid >> 5;
    const int g4   = (tid >> 3) & 3;
    const int l8   = tid & 7;
    const int c0   = 4*l8;
    const int kp   = g4*8;

    float acc[10][4];
#pragma unroll
    for (int n=0;n<10;++n) { acc[n][0]=0.f; acc[n][1]=0.f; acc[n][2]=0.f; acc[n][3]=0.f; }

    {
        const float* Wb = sign ? Wb_neg : Wb_pos;
        const float* fb0 = sign ? &Sm[1][0][0] : &Sm[0][0][0];
#pragma unroll
        for (int blk = 0; blk < 4; ++blk) {
            const float* bp = ((blk < 2) ? fb0 : &Sx[0][0]) + (blk & 1)*32 + kp;
            const float* wrow = Wb + (blk*32 + kp)*32 + c0;
            for (int kk = 0; kk < 8; ++kk) {
                float4 w = *(const float4*)(wrow + kk*32);
#pragma unroll
                for (int n = 0; n < 10; ++n) {
                    float f = bp[n*64 + kk];
                    acc[n][0] += f*w.x; acc[n][1] += f*w.y;
                    acc[n][2] += f*w.z; acc[n][3] += f*w.w;
                }
            }
        }
    }
#pragma unroll
    for (int n=0;n<10;++n)
#pragma unroll
        for (int q=0;q<4;++q) {
            float v = acc[n][q];
            v += __shfl_xor(v, 8);
            v += __shfl_xor(v, 16);
            acc[n][q] = v;
        }
    {
        const float* bb = sign ? bb_neg : bb_pos;
        float4 b4 = *(const float4*)(bb + c0);
#pragma unroll
        for (int n=0;n<10;++n) {
            acc[n][0]+=b4.x; acc[n][1]+=b4.y; acc[n][2]+=b4.z; acc[n][3]+=b4.w;
            float s = acc[n][0]*acc[n][0]+acc[n][1]*acc[n][1]
                    + acc[n][2]*acc[n][2]+acc[n][3]*acc[n][3];
            s += __shfl_xor(s,1); s += __shfl_xor(s,2); s += __shfl_xor(s,4);
            float rn = 1.f / fmaxf(sqrtf(s), 1e-12f);
            if (g4 == 0) {
                Sh[sign][n][c0+0] = acc[n][0]*rn;
                Sh[sign][n][c0+1] = acc[n][1]*rn;
                Sh[sign][n][c0+2] = acc[n][2]*rn;
                Sh[sign][n][c0+3] = acc[n][3]*rn;
            }
        }
    }
    __syncthreads();

    const int colv = tid & 31;
    for (int l = 0; l < 2; ++l) {
        for (int i = tid; i < 1920; i += 64) ((float*)Sagg)[i] = 0.f;
        __syncthreads();
        {
            const int e0 = 2*sign, e1 = 2*sign + 1;
            const int bA = sign ? 2 : 0;
            const int bC = sign ? 5 : 4;
            for (int e = 0; e < 40; ++e) {
                int sn = Ses[e0][e], dn = Ses[e1][e];
                Sagg[bA][sn][colv] += Sh[sign][dn][colv];
            }
            for (int e = 0; e < 40; ++e) {
                int sn = Ses[e0][e], dn = Ses[e1][e];
                Sagg[bA+1][dn][colv] += Sh[sign][sn][colv];
            }
            for (int e = 0; e < 40; ++e) {
                int sn = Ses[e0][e], dn = Ses[e1][e];
                Sagg[bC][sn][colv] += Sh[1-sign][dn][colv];
            }
        }
        __syncthreads();
        {
            for (int i = tid; i < 1920; i += 64) {
                int b = i / 320, n = (i % 320) / 32;
                int ci = (b==0)?0:(b==1)?1:(b==2)?2:(b==3)?3:(b==4)?0:2;
                ((float*)Sagg)[i] /= fmaxf((float)Scnt[ci][n], 1.f);
            }
        }
        __syncthreads();
#pragma unroll
        for (int n=0;n<10;++n) { acc[n][0]=0.f; acc[n][1]=0.f; acc[n][2]=0.f; acc[n][3]=0.f; }
        {
            const float* ord[7];
            if (sign == 0) {
                ord[0]=&Sagg[0][0][0]; ord[1]=&Sagg[1][0][0]; ord[2]=&Sagg[2][0][0];
                ord[3]=&Sagg[3][0][0]; ord[4]=&Sagg[4][0][0];
                ord[5]=&Sh[0][0][0];   ord[6]=&Sh[1][0][0];
            } else {
                ord[0]=&Sagg[2][0][0]; ord[1]=&Sagg[3][0][0]; ord[2]=&Sagg[0][0][0];
                ord[3]=&Sagg[1][0][0]; ord[4]=&Sagg[5][0][0];
                ord[5]=&Sh[1][0][0];   ord[6]=&Sh[0][0][0];
            }
            const float* Wd = (sign ? Wd_neg : Wd_pos) + l*7168;
            for (int blk = 0; blk < 7; ++blk) {
                const float* bp = ord[blk] + kp;
                const float* wrow = Wd + (blk*32 + kp)*32 + c0;
                for (int kk = 0; kk < 8; ++kk) {
                    float4 w = *(const float4*)(wrow + kk*32);
#pragma unroll
                    for (int n = 0; n < 10; ++n) {
                        float f = bp[n*32 + kk];
                        acc[n][0] += f*w.x; acc[n][1] += f*w.y;
                        acc[n][2] += f*w.z; acc[n][3] += f*w.w;
                    }
                }
            }
        }
#pragma unroll
        for (int n=0;n<10;++n)
#pragma unroll
            for (int q=0;q<4;++q) {
                float v = acc[n][q];
                v += __shfl_xor(v, 8);
                v += __shfl_xor(v, 16);
                acc[n][q] = v;
            }
        {
            const float* bd = (sign ? bd_neg : bd_pos) + l*32;
            float4 b4 = *(const float4*)(bd + c0);
#pragma unroll
            for (int n=0;n<10;++n) {
                acc[n][0]+=b4.x; acc[n][1]+=b4.y; acc[n][2]+=b4.z; acc[n][3]+=b4.w;
                float s = acc[n][0]*acc[n][0]+acc[n][1]*acc[n][1]
                        + acc[n][2]*acc[n][2]+acc[n][3]*acc[n][3];
                s += __shfl_xor(s,1); s += __shfl_xor(s,2); s += __shfl_xor(s,4);
                float rn = 1.f / fmaxf(sqrtf(s), 1e-12f);
                if (g4 == 0) {
                    Shn[sign][n][c0+0]=acc[n][0]*rn; Shn[sign][n][c0+1]=acc[n][1]*rn;
                    Shn[sign][n][c0+2]=acc[n][2]*rn; Shn[sign][n][c0+3]=acc[n][3]*rn;
                }
            }
        }
        __syncthreads();
        for (int i = tid; i < 640; i += 64) ((float*)Sh)[i] = ((float*)Shn)[i];
        __syncthreads();
    }

#pragma unroll
    for (int n = 0; n < 10; ++n) {
        float v = (tid < 32) ? Sh[0][n][tid] : Sh[1][n][tid-32];
        emb[(nb+n)*64 + tid] = v;
    }
}

// ---------------------------------------------------------------------------
// Persistent MFMA LSTM: 160 blocks x 512 threads (8 waves). Block owns 32 rows
// and all 512 gate-columns. Split-bf16 (hi+lo) precision: acc += Ah*Bh + Ah*Bl
// + Al*Bh. Wave w owns n-tiles {w, w+8, w+16, w+24} so each lane holds all 4
// gates of (row, j) in registers -> thread-local c/h update, 2 barriers/step.
// A-panel (x|h as bf16 hi/lo) in LDS in MFMA fragment layout; B from global.
// ---------------------------------------------------------------------------
__global__ __launch_bounds__(512) void lstm_mfma(
    const float* __restrict__ emb, const float* __restrict__ add_info,
    const short* __restrict__ wB, const float* __restrict__ wadd,
    const float* __restrict__ bsum, const float* __restrict__ hx0,
    const float* __restrict__ cx0, float* __restrict__ hbuf)
{
    __shared__ short aP[12288];          // [2][6][2][64][8] bf16 bits, 24.6 KB
    __shared__ float Sadd[2][32][2];
    const int tid = threadIdx.x;
    const int w  = tid >> 6;             // wave 0..7
    const int l  = tid & 63;
    const int li = l & 15;
    const int lk = l >> 4;
    const int R0 = blockIdx.x * 32;

    // ---- init h_0 into aP ki 0..3 ----
    {
        int row = tid >> 4, j0 = (tid & 15) * 8;
        const float* hp = hx0 + (size_t)(R0 + row)*128 + j0;
        float4 h0 = *(const float4*)hp;
        float4 h1 = *(const float4*)(hp + 4);
        float v[8] = {h0.x,h0.y,h0.z,h0.w,h1.x,h1.y,h1.z,h1.w};
        short8v hi, lo;
#pragma unroll
        for (int e = 0; e < 8; ++e) {
            unsigned short hs = f2bf(v[e]);
            hi[e] = (short)hs;
            lo[e] = (short)f2bf(v[e] - bf2f(hs));
        }
        int mt = row >> 4, ln = (row & 15) + 16*((j0 >> 3) & 3), ki = j0 >> 5;
        *(short8v*)&aP[AIDX(0,ki,mt,ln)] = hi;
        *(short8v*)&aP[AIDX(1,ki,mt,ln)] = lo;
    }
    // ---- stage x_0 into aP ki 4,5 ----
    {
        int row = tid >> 4, d0 = (tid & 15)*4;
        int R = R0 + row, g = R/10, p = R - 10*g;
        float4 f = *(const float4*)&emb[((size_t)(g*TT + 0)*PP + p)*64 + d0];
        int k0 = 128 + d0;
        int mt = row>>4, ln = (row&15) + 16*((k0>>3)&3), ki = k0>>5, e0 = k0&7;
        float v[4] = {f.x,f.y,f.z,f.w};
        short4v hi, lo;
#pragma unroll
        for (int e = 0; e < 4; ++e) {
            unsigned short hs = f2bf(v[e]);
            hi[e] = (short)hs;
            lo[e] = (short)f2bf(v[e] - bf2f(hs));
        }
        *(short4v*)&aP[AIDX(0,ki,mt,ln)+e0] = hi;
        *(short4v*)&aP[AIDX(1,ki,mt,ln)+e0] = lo;
    }
    if (tid < 64) {
        int row = tid >> 1, cc = tid & 1;
        int R = R0 + row, g = R/10, p = R - 10*g;
        Sadd[0][row][cc] = add_info[((size_t)(g*MM + 0)*PP + p)*2 + cc];
    }
    // ---- init c (thread-local, 8 per thread) ----
    float c[2][4];
#pragma unroll
    for (int mt = 0; mt < 2; ++mt)
#pragma unroll
        for (int r = 0; r < 4; ++r) {
            int row = mt*16 + lk*4 + r;
            c[mt][r] = cx0[(size_t)(R0+row)*128 + 16*w + li];
        }
    __syncthreads();

    for (int t = 0; t < TT; ++t) {
        f32x4 acc[2][4];
#pragma unroll
        for (int g = 0; g < 4; ++g) {
            float bs = bsum[t*512 + 128*g + 16*w + li];
            acc[0][g] = (f32x4){bs,bs,bs,bs};
            acc[1][g] = (f32x4){bs,bs,bs,bs};
        }
        const short* wt = wB + (size_t)t * WB_PER_T;
#pragma unroll 2
        for (int ki = 0; ki < 6; ++ki) {
            short8v ah0 = *(const short8v*)&aP[AIDX(0,ki,0,l)];
            short8v ah1 = *(const short8v*)&aP[AIDX(0,ki,1,l)];
            short8v al0 = *(const short8v*)&aP[AIDX(1,ki,0,l)];
            short8v al1 = *(const short8v*)&aP[AIDX(1,ki,1,l)];
#pragma unroll
            for (int g = 0; g < 4; ++g) {
                int nt = w + 8*g;
                short8v bh = *(const short8v*)(wt + (((size_t)ki*32 + nt)*64 + l)*8);
                short8v bl = *(const short8v*)(wt + (((size_t)(6+ki)*32 + nt)*64 + l)*8);
                acc[0][g] = __builtin_amdgcn_mfma_f32_16x16x32_bf16(ah0, bh, acc[0][g], 0, 0, 0);
                acc[0][g] = __builtin_amdgcn_mfma_f32_16x16x32_bf16(ah0, bl, acc[0][g], 0, 0, 0);
                acc[0][g] = __builtin_amdgcn_mfma_f32_16x16x32_bf16(al0, bh, acc[0][g], 0, 0, 0);
                acc[1][g] = __builtin_amdgcn_mfma_f32_16x16x32_bf16(ah1, bh, acc[1][g], 0, 0, 0);
                acc[1][g] = __builtin_amdgcn_mfma_f32_16x16x32_bf16(ah1, bl, acc[1][g], 0, 0, 0);
                acc[1][g] = __builtin_amdgcn_mfma_f32_16x16x32_bf16(al1, bh, acc[1][g], 0, 0, 0);
            }
        }
        __syncthreads();   // all aP reads done

        // ---- epilogue: add_info rank-2 update, gates, c/h update ----
        float wa0[4], wa1[4];
#pragma unroll
        for (int g = 0; g < 4; ++g) {
            wa0[g] = wadd[(size_t)(t*2+0)*512 + 128*g + 16*w + li];
            wa1[g] = wadd[(size_t)(t*2+1)*512 + 128*g + 16*w + li];
        }
        const int sb = t & 1;
        const int j  = 16*w + li;
        const int jsh = 16*((j >> 3) & 3);
        const int jki = j >> 5;
        const int je  = j & 7;
#pragma unroll
        for (int mt = 0; mt < 2; ++mt) {
#pragma unroll
            for (int r = 0; r < 4; ++r) {
                int row = mt*16 + lk*4 + r;
                float ad0 = Sadd[sb][row][0], ad1 = Sadd[sb][row][1];
                float v0 = acc[mt][0][r] + ad0*wa0[0] + ad1*wa1[0];
                float v1 = acc[mt][1][r] + ad0*wa0[1] + ad1*wa1[1];
                float v2 = acc[mt][2][r] + ad0*wa0[2] + ad1*wa1[2];
                float v3 = acc[mt][3][r] + ad0*wa0[3] + ad1*wa1[3];
                float iv = sigm(v0);
                float fv = sigm(v1);
                float gv = tanh_fast(v2);
                float ov = sigm(v3);
                float cn = fv*c[mt][r] + iv*gv;
                c[mt][r] = cn;
                float hv = ov*tanh_fast(cn);
                unsigned short hs = f2bf(hv);
                int ln = (row & 15) + jsh;
                aP[AIDX(0, jki, mt, ln) + je] = (short)hs;
                aP[AIDX(1, jki, mt, ln) + je] = (short)f2bf(hv - bf2f(hs));
                if (t == TT-1) hbuf[(size_t)(R0+row)*128 + j] = hv;
            }
        }
        if (t < TT-1) {
            int row = tid >> 4, d0 = (tid & 15)*4;
            int R = R0 + row, g = R/10, p = R - 10*g;
            float4 f = *(const float4*)&emb[((size_t)(g*TT + (t+1))*PP + p)*64 + d0];
            int k0 = 128 + d0;
            int mt = row>>4, ln = (row&15) + 16*((k0>>3)&3), ki = k0>>5, e0 = k0&7;
            float v[4] = {f.x,f.y,f.z,f.w};
            short4v hi, lo;
#pragma unroll
            for (int e = 0; e < 4; ++e) {
                unsigned short hs = f2bf(v[e]);
                hi[e] = (short)hs;
                lo[e] = (short)f2bf(v[e] - bf2f(hs));
            }
            *(short4v*)&aP[AIDX(0,ki,mt,ln)+e0] = hi;
            *(short4v*)&aP[AIDX(1,ki,mt,ln)+e0] = lo;
            if (tid < 64) {
                int rw = tid >> 1, cc = tid & 1;
                int R2 = R0 + rw, g2 = R2/10, p2 = R2 - 10*g2;
                Sadd[sb^1][rw][cc] =
                    add_info[((size_t)(g2*MM + (t+1)/MM)*PP + p2)*2 + cc];
            }
        }
        __syncthreads();   // aP/Sadd ready for next step
    }
}

// ---------------------------------------------------------------------------
// Final projection: out = h_last @ Wf + bf
// ---------------------------------------------------------------------------
__global__ __launch_bounds__(256) void final_proj(
    const float* __restrict__ hbuf, const float* __restrict__ Wf,
    const float* __restrict__ bf, float* __restrict__ out)
{
    __shared__ float wl[128*32];
    __shared__ float hl[64][128];
    const int tid = threadIdx.x;
    const int row0 = blockIdx.x * 64;
    for (int i = tid; i < 4096; i += 256) wl[i] = Wf[i];
    for (int i = tid; i < 8192; i += 256) hl[i>>7][i&127] = hbuf[row0*128 + i];
    __syncthreads();
    const int e  = tid & 31;
    const int rg = tid >> 5;
    float b = bf[e];
    float acc[8];
#pragma unroll
    for (int r=0;r<8;++r) acc[r] = b;
    for (int k = 0; k < 128; ++k) {
        float ww = wl[k*32 + e];
#pragma unroll
        for (int r=0;r<8;++r) acc[r] += hl[rg*8+r][k]*ww;
    }
#pragma unroll
    for (int r=0;r<8;++r) out[(row0 + rg*8 + r)*32 + e] = acc[r];
}

// ---------------------------------------------------------------------------
extern "C" void kernel_launch(void* const* d_in, const int* in_sizes, int n_in,
                              void* d_out, int out_size, void* d_ws, size_t ws_size,
                              hipStream_t stream)
{
    const float* x0       = (const float*)d_in[0];
    const float* add_info = (const float*)d_in[1];
    const float* Wb_pos   = (const float*)d_in[2];
    const float* bb_pos   = (const float*)d_in[3];
    const float* Wb_neg   = (const float*)d_in[4];
    const float* bb_neg   = (const float*)d_in[5];
    const float* Wd_pos   = (const float*)d_in[6];
    const float* bd_pos   = (const float*)d_in[7];
    const float* Wd_neg   = (const float*)d_in[8];
    const float* bd_neg   = (const float*)d_in[9];
    const float* W_ih     = (const float*)d_in[10];
    const float* W_hh     = (const float*)d_in[11];
    const float* b_ih     = (const float*)d_in[12];
    const float* b_hh     = (const float*)d_in[13];
    const float* hx0      = (const float*)d_in[14];
    const float* cx0      = (const float*)d_in[15];
    const float* Wf       = (const float*)d_in[16];
    const float* bf       = (const float*)d_in[17];
    const int*   pos_src  = (const int*)d_in[18];
    const int*   pos_dst  = (const int*)d_in[19];
    const int*   neg_src  = (const int*)d_in[20];
    const int*   neg_dst  = (const int*)d_in[21];

    float* ws    = (float*)d_ws;
    float* emb   = ws;                        // 8,192,000 f32
    float* hbuf  = emb   + 8192000;           //   655,360 f32
    float* bsumw = hbuf  + 655360;            //    12,800 f32
    float* waddw = bsumw + 12800;             //    25,600 f32
    short* wBw   = (short*)(waddw + 25600);   // 4,915,200 bf16-bits (~45.4 MiB total)

    hipLaunchKernelGGL(prep_kernel, dim3(2048), dim3(256), 0, stream,
                       W_ih, W_hh, b_ih, b_hh, wBw, waddw, bsumw);
    hipLaunchKernelGGL(graph_kernel, dim3(NGRAPH), dim3(64), 0, stream,
                       x0, Wb_pos, bb_pos, Wb_neg, bb_neg,
                       Wd_pos, bd_pos, Wd_neg, bd_neg,
                       pos_src, pos_dst, neg_src, neg_dst, emb);
    hipLaunchKernelGGL(lstm_mfma, dim3(160), dim3(512), 0, stream,
                       emb, add_info, wBw, waddw, bsumw, hx0, cx0, hbuf);
    hipLaunchKernelGGL(final_proj, dim3(80), dim3(256), 0, stream,
                       hbuf, Wf, bf, (float*)d_out);
}

// Round 5
// 543.701 us; speedup vs baseline: 2.2286x; 1.2689x over previous
//
#include <hip/hip_runtime.h>
#include <math.h>

#define GG 512
#define TT 25
#define PP 10
#define MM 5
#define EE 32
#define HID 32
#define HH 128
#define NEDGE 40
#define NGRAPH (GG*TT)          // 12800
#define NTOT (GG*TT*PP)         // 128000

typedef __attribute__((ext_vector_type(8))) short short8v;
typedef __attribute__((ext_vector_type(4))) short short4v;
typedef __attribute__((ext_vector_type(4))) float f32x4;

// A-panel LDS index: [s][ki<6][mt<2][lane<64][e<8] (shorts)
#define AIDX(s,ki,mt,l) (((((s)*6+(ki))*2+(mt))*64+(l))*8)
#define WB_PER_T 196608   // 2*6*32*64*8

__device__ __forceinline__ unsigned short f2bf(float x){
    unsigned u = __float_as_uint(x);
    u += 0x7fffu + ((u >> 16) & 1u);
    return (unsigned short)(u >> 16);
}
__device__ __forceinline__ float bf2f(unsigned short s){
    return __uint_as_float(((unsigned)s) << 16);
}
__device__ __forceinline__ float sigm(float x){ return 1.f/(1.f+__expf(-x)); }
__device__ __forceinline__ float tanh_fast(float x){
    float ax = fabsf(x);
    float e  = __expf(-2.f*ax);
    float t  = (1.f-e)/(1.f+e);
    return copysignf(t, x);
}

// ---------------------------------------------------------------------------
// Prep: build MFMA-fragment weight tensor wB[t][s][ki][nt][lane][e] (bf16 bits)
// ---------------------------------------------------------------------------
__global__ void prep_kernel(const float* __restrict__ W_ih, const float* __restrict__ W_hh,
                            const float* __restrict__ b_ih, const float* __restrict__ b_hh,
                            short* __restrict__ wB, float* __restrict__ wadd,
                            float* __restrict__ bsum)
{
    const int NW = TT*WB_PER_T;          // 4,915,200
    const int NA = TT*2*512;             // 25,600
    const int NB = TT*512;               // 12,800
    for (int idx = blockIdx.x*blockDim.x + threadIdx.x; idx < NW+NA+NB;
         idx += gridDim.x*blockDim.x) {
        if (idx < NW) {
            int e  = idx & 7;
            int l  = (idx >> 3) & 63;
            int nt = (idx >> 9) & 31;
            int rest = idx >> 14;        // (t*2+s)*6 + ki
            int ki = rest % 6; rest /= 6;
            int s  = rest & 1;
            int t  = rest >> 1;
            int k  = ki*32 + (l >> 4)*8 + e;
            int n  = nt*16 + (l & 15);
            float wv = (k < 128) ? W_hh[(size_t)(t*512 + n)*128 + k]
                                 : W_ih[(size_t)(t*512 + n)*66 + (k - 128)];
            unsigned short hi = f2bf(wv);
            unsigned short outv = (s == 0) ? hi : f2bf(wv - bf2f(hi));
            wB[idx] = (short)outv;
        } else if (idx < NW + NA) {
            int i2 = idx - NW;
            int t = i2 / 1024, r = i2 % 1024;
            int cc = r >> 9, n = r & 511;
            wadd[i2] = W_ih[(size_t)(t*512 + n)*66 + 64 + cc];
        } else {
            int i3 = idx - NW - NA;
            bsum[i3] = b_ih[i3] + b_hh[i3];
        }
    }
}

// ---------------------------------------------------------------------------
// Graph kernel v2: one 64-thread block per (g,t) vote graph.
// Aggregations are dense adjacency matmuls (no serial LDS RMW chains):
//   C_pos/C_neg built via LDS atomics once; 4 normalized adjacencies
//   P_in/P_out/N_in/N_out drive every seg_mean as a 10x10 @ 10xD matmul.
// LDS trimmed to ~16 KB (Sm/Sagg union, in-place Sh update).
// ---------------------------------------------------------------------------
__global__ __launch_bounds__(64) void graph_kernel(
    const float* __restrict__ x0,
    const float* __restrict__ Wb_pos, const float* __restrict__ bb_pos,
    const float* __restrict__ Wb_neg, const float* __restrict__ bb_neg,
    const float* __restrict__ Wd_pos, const float* __restrict__ bd_pos,
    const float* __restrict__ Wd_neg, const float* __restrict__ bd_neg,
    const int* __restrict__ pos_src, const int* __restrict__ pos_dst,
    const int* __restrict__ neg_src, const int* __restrict__ neg_dst,
    float* __restrict__ emb)
{
    __shared__ float Sx[10][64];        // 2560 B
    __shared__ float Su[1920];          // 7680 B union: Sm[2][10][64] / Sagg[6][10][32]
    __shared__ float Sh[2][10][32];     // 2560 B
    __shared__ float Adj[4][10][10];    // 1600 B  (P_in, P_out, N_in, N_out)
    __shared__ float Cm[2][10][10];     //  800 B
    __shared__ float Scnt[4][10];       //  160 B
    __shared__ int   Ses[4][40];        //  640 B   total ~16 KB

    const int gid = blockIdx.x;
    const int nb  = gid * PP;
    const int tid = threadIdx.x;

    for (int i = tid; i < 640; i += 64) ((float*)Sx)[i] = x0[nb*64 + i];
    for (int i = tid; i < 160; i += 64) {
        int b = i / 40, e = i % 40;
        const int* p = (b==0)?pos_src:(b==1)?pos_dst:(b==2)?neg_src:neg_dst;
        ((int*)Ses)[i] = p[gid*40 + e];
    }
    for (int i = tid; i < 200; i += 64) ((float*)Cm)[i] = 0.f;
    __syncthreads();

    if (tid < 40) {
        atomicAdd(&Cm[0][Ses[0][tid]][Ses[1][tid]], 1.f);
        atomicAdd(&Cm[1][Ses[2][tid]][Ses[3][tid]], 1.f);
    }
    __syncthreads();
    if (tid < 40) {
        int b = tid / 10, n = tid % 10;
        int si = b >> 1, isCol = b & 1;
        float s = 0.f;
        for (int m = 0; m < 10; ++m)
            s += isCol ? Cm[si][m][n] : Cm[si][n][m];
        Scnt[b][n] = fmaxf(s, 1.f);
    }
    __syncthreads();
    for (int i = tid; i < 400; i += 64) {
        int a = i / 100, r = i % 100, n = r / 10, m = r % 10;
        int si = a >> 1, isOut = a & 1;
        float cv = isOut ? Cm[si][m][n] : Cm[si][n][m];
        Adj[a][n][m] = cv / Scnt[si*2 + isOut][n];
    }
    __syncthreads();

    // ---- base means via adjacency matmul: thread owns dim d ----
    {
        const int d = tid;
        float xr[10];
#pragma unroll
        for (int m = 0; m < 10; ++m) xr[m] = Sx[m][d];
        float* Sm = Su;   // [2][10][64]
#pragma unroll
        for (int n = 0; n < 10; ++n) {
            float mp = 0.f, mn2 = 0.f;
#pragma unroll
            for (int m = 0; m < 10; ++m) {
                mp  += Adj[0][n][m] * xr[m];
                mn2 += Adj[2][n][m] * xr[m];
            }
            Sm[(0*10 + n)*64 + d] = mp;
            Sm[(1*10 + n)*64 + d] = mn2;
        }
    }
    __syncthreads();

    const int sign = tid >> 5;
    const int g4   = (tid >> 3) & 3;
    const int l8   = tid & 7;
    const int c0   = 4*l8;
    const int kp   = g4*8;
    const int cv   = tid & 31;

    float acc[10][4];
#pragma unroll
    for (int n=0;n<10;++n) { acc[n][0]=0.f; acc[n][1]=0.f; acc[n][2]=0.f; acc[n][3]=0.f; }

    // ---- base GEMM: feats = [mean_in(64) | x(64)], W (128x32) ----
    {
        const float* Wb = sign ? Wb_neg : Wb_pos;
        const float* fb0 = Su + sign*640;
#pragma unroll
        for (int blk = 0; blk < 4; ++blk) {
            const float* bp = ((blk < 2) ? fb0 : &Sx[0][0]) + (blk & 1)*32 + kp;
            const float* wrow = Wb + (blk*32 + kp)*32 + c0;
            for (int kk = 0; kk < 8; ++kk) {
                float4 w = *(const float4*)(wrow + kk*32);
#pragma unroll
                for (int n = 0; n < 10; ++n) {
                    float f = bp[n*64 + kk];
                    acc[n][0] += f*w.x; acc[n][1] += f*w.y;
                    acc[n][2] += f*w.z; acc[n][3] += f*w.w;
                }
            }
        }
    }
#pragma unroll
    for (int n=0;n<10;++n)
#pragma unroll
        for (int q=0;q<4;++q) {
            float v = acc[n][q];
            v += __shfl_xor(v, 8);
            v += __shfl_xor(v, 16);
            acc[n][q] = v;
        }
    {
        const float* bb = sign ? bb_neg : bb_pos;
        float4 b4 = *(const float4*)(bb + c0);
#pragma unroll
        for (int n=0;n<10;++n) {
            acc[n][0]+=b4.x; acc[n][1]+=b4.y; acc[n][2]+=b4.z; acc[n][3]+=b4.w;
            float s = acc[n][0]*acc[n][0]+acc[n][1]*acc[n][1]
                    + acc[n][2]*acc[n][2]+acc[n][3]*acc[n][3];
            s += __shfl_xor(s,1); s += __shfl_xor(s,2); s += __shfl_xor(s,4);
            float rn = 1.f / fmaxf(sqrtf(s), 1e-12f);
            if (g4 == 0) {
                Sh[sign][n][c0+0] = acc[n][0]*rn;
                Sh[sign][n][c0+1] = acc[n][1]*rn;
                Sh[sign][n][c0+2] = acc[n][2]*rn;
                Sh[sign][n][c0+3] = acc[n][3]*rn;
            }
        }
    }
    __syncthreads();

    // ---- two deep layers ----
    float* Sagg = Su;   // [6][10][32]
    for (int l = 0; l < 2; ++l) {
        // aggregates via adjacency matmul: thread owns (sign, cv)
        {
            float hs[10], ho[10];
#pragma unroll
            for (int m = 0; m < 10; ++m) {
                hs[m] = Sh[sign][m][cv];
                ho[m] = Sh[1-sign][m][cv];
            }
            const int aIn = 2*sign, aOut = 2*sign + 1;
#pragma unroll
            for (int n = 0; n < 10; ++n) {
                float ai = 0.f, ao = 0.f, ac = 0.f;
#pragma unroll
                for (int m = 0; m < 10; ++m) {
                    float w1 = Adj[aIn][n][m];
                    ai += w1 * hs[m];
                    ac += w1 * ho[m];
                    ao += Adj[aOut][n][m] * hs[m];
                }
                Sagg[(aIn*10 + n)*32 + cv]      = ai;
                Sagg[(aOut*10 + n)*32 + cv]     = ao;
                Sagg[((4+sign)*10 + n)*32 + cv] = ac;
            }
        }
        __syncthreads();

#pragma unroll
        for (int n=0;n<10;++n) { acc[n][0]=0.f; acc[n][1]=0.f; acc[n][2]=0.f; acc[n][3]=0.f; }
        {
            const float* ord[7];
            if (sign == 0) {
                ord[0]=Sagg+0*320; ord[1]=Sagg+1*320; ord[2]=Sagg+2*320;
                ord[3]=Sagg+3*320; ord[4]=Sagg+4*320;
                ord[5]=&Sh[0][0][0]; ord[6]=&Sh[1][0][0];
            } else {
                ord[0]=Sagg+2*320; ord[1]=Sagg+3*320; ord[2]=Sagg+0*320;
                ord[3]=Sagg+1*320; ord[4]=Sagg+5*320;
                ord[5]=&Sh[1][0][0]; ord[6]=&Sh[0][0][0];
            }
            const float* Wd = (sign ? Wd_neg : Wd_pos) + l*7168;
            for (int blk = 0; blk < 7; ++blk) {
                const float* bp = ord[blk] + kp;
                const float* wrow = Wd + (blk*32 + kp)*32 + c0;
                for (int kk = 0; kk < 8; ++kk) {
                    float4 w = *(const float4*)(wrow + kk*32);
#pragma unroll
                    for (int n = 0; n < 10; ++n) {
                        float f = bp[n*32 + kk];
                        acc[n][0] += f*w.x; acc[n][1] += f*w.y;
                        acc[n][2] += f*w.z; acc[n][3] += f*w.w;
                    }
                }
            }
        }
#pragma unroll
        for (int n=0;n<10;++n)
#pragma unroll
            for (int q=0;q<4;++q) {
                float v = acc[n][q];
                v += __shfl_xor(v, 8);
                v += __shfl_xor(v, 16);
                acc[n][q] = v;
            }
        {
            const float* bd = (sign ? bd_neg : bd_pos) + l*32;
            float4 b4 = *(const float4*)(bd + c0);
#pragma unroll
            for (int n=0;n<10;++n) {
                float v0=acc[n][0]+b4.x, v1=acc[n][1]+b4.y,
                      v2=acc[n][2]+b4.z, v3=acc[n][3]+b4.w;
                float s = v0*v0+v1*v1+v2*v2+v3*v3;
                s += __shfl_xor(s,1); s += __shfl_xor(s,2); s += __shfl_xor(s,4);
                float rn = 1.f / fmaxf(sqrtf(s), 1e-12f);
                acc[n][0]=v0*rn; acc[n][1]=v1*rn; acc[n][2]=v2*rn; acc[n][3]=v3*rn;
            }
        }
        __syncthreads();    // all Sh/Sagg reads complete
        if (g4 == 0) {
#pragma unroll
            for (int n=0;n<10;++n) {
                Sh[sign][n][c0+0]=acc[n][0]; Sh[sign][n][c0+1]=acc[n][1];
                Sh[sign][n][c0+2]=acc[n][2]; Sh[sign][n][c0+3]=acc[n][3];
            }
        }
        __syncthreads();    // new Sh visible
    }

#pragma unroll
    for (int n = 0; n < 10; ++n) {
        float v = (tid < 32) ? Sh[0][n][tid] : Sh[1][n][tid-32];
        emb[(nb+n)*64 + tid] = v;
    }
}

// ---------------------------------------------------------------------------
// Persistent MFMA LSTM (unchanged from round 4).
// ---------------------------------------------------------------------------
__global__ __launch_bounds__(512) void lstm_mfma(
    const float* __restrict__ emb, const float* __restrict__ add_info,
    const short* __restrict__ wB, const float* __restrict__ wadd,
    const float* __restrict__ bsum, const float* __restrict__ hx0,
    const float* __restrict__ cx0, float* __restrict__ hbuf)
{
    __shared__ short aP[12288];          // [2][6][2][64][8] bf16 bits, 24.6 KB
    __shared__ float Sadd[2][32][2];
    const int tid = threadIdx.x;
    const int w  = tid >> 6;             // wave 0..7
    const int l  = tid & 63;
    const int li = l & 15;
    const int lk = l >> 4;
    const int R0 = blockIdx.x * 32;

    {
        int row = tid >> 4, j0 = (tid & 15) * 8;
        const float* hp = hx0 + (size_t)(R0 + row)*128 + j0;
        float4 h0 = *(const float4*)hp;
        float4 h1 = *(const float4*)(hp + 4);
        float v[8] = {h0.x,h0.y,h0.z,h0.w,h1.x,h1.y,h1.z,h1.w};
        short8v hi, lo;
#pragma unroll
        for (int e = 0; e < 8; ++e) {
            unsigned short hs = f2bf(v[e]);
            hi[e] = (short)hs;
            lo[e] = (short)f2bf(v[e] - bf2f(hs));
        }
        int mt = row >> 4, ln = (row & 15) + 16*((j0 >> 3) & 3), ki = j0 >> 5;
        *(short8v*)&aP[AIDX(0,ki,mt,ln)] = hi;
        *(short8v*)&aP[AIDX(1,ki,mt,ln)] = lo;
    }
    {
        int row = tid >> 4, d0 = (tid & 15)*4;
        int R = R0 + row, g = R/10, p = R - 10*g;
        float4 f = *(const float4*)&emb[((size_t)(g*TT + 0)*PP + p)*64 + d0];
        int k0 = 128 + d0;
        int mt = row>>4, ln = (row&15) + 16*((k0>>3)&3), ki = k0>>5, e0 = k0&7;
        float v[4] = {f.x,f.y,f.z,f.w};
        short4v hi, lo;
#pragma unroll
        for (int e = 0; e < 4; ++e) {
            unsigned short hs = f2bf(v[e]);
            hi[e] = (short)hs;
            lo[e] = (short)f2bf(v[e] - bf2f(hs));
        }
        *(short4v*)&aP[AIDX(0,ki,mt,ln)+e0] = hi;
        *(short4v*)&aP[AIDX(1,ki,mt,ln)+e0] = lo;
    }
    if (tid < 64) {
        int row = tid >> 1, cc = tid & 1;
        int R = R0 + row, g = R/10, p = R - 10*g;
        Sadd[0][row][cc] = add_info[((size_t)(g*MM + 0)*PP + p)*2 + cc];
    }
    float c[2][4];
#pragma unroll
    for (int mt = 0; mt < 2; ++mt)
#pragma unroll
        for (int r = 0; r < 4; ++r) {
            int row = mt*16 + lk*4 + r;
            c[mt][r] = cx0[(size_t)(R0+row)*128 + 16*w + li];
        }
    __syncthreads();

    for (int t = 0; t < TT; ++t) {
        f32x4 acc[2][4];
#pragma unroll
        for (int g = 0; g < 4; ++g) {
            float bs = bsum[t*512 + 128*g + 16*w + li];
            acc[0][g] = (f32x4){bs,bs,bs,bs};
            acc[1][g] = (f32x4){bs,bs,bs,bs};
        }
        const short* wt = wB + (size_t)t * WB_PER_T;
#pragma unroll 2
        for (int ki = 0; ki < 6; ++ki) {
            short8v ah0 = *(const short8v*)&aP[AIDX(0,ki,0,l)];
            short8v ah1 = *(const short8v*)&aP[AIDX(0,ki,1,l)];
            short8v al0 = *(const short8v*)&aP[AIDX(1,ki,0,l)];
            short8v al1 = *(const short8v*)&aP[AIDX(1,ki,1,l)];
#pragma unroll
            for (int g = 0; g < 4; ++g) {
                int nt = w + 8*g;
                short8v bh = *(const short8v*)(wt + (((size_t)ki*32 + nt)*64 + l)*8);
                short8v bl = *(const short8v*)(wt + (((size_t)(6+ki)*32 + nt)*64 + l)*8);
                acc[0][g] = __builtin_amdgcn_mfma_f32_16x16x32_bf16(ah0, bh, acc[0][g], 0, 0, 0);
                acc[0][g] = __builtin_amdgcn_mfma_f32_16x16x32_bf16(ah0, bl, acc[0][g], 0, 0, 0);
                acc[0][g] = __builtin_amdgcn_mfma_f32_16x16x32_bf16(al0, bh, acc[0][g], 0, 0, 0);
                acc[1][g] = __builtin_amdgcn_mfma_f32_16x16x32_bf16(ah1, bh, acc[1][g], 0, 0, 0);
                acc[1][g] = __builtin_amdgcn_mfma_f32_16x16x32_bf16(ah1, bl, acc[1][g], 0, 0, 0);
                acc[1][g] = __builtin_amdgcn_mfma_f32_16x16x32_bf16(al1, bh, acc[1][g], 0, 0, 0);
            }
        }
        __syncthreads();

        float wa0[4], wa1[4];
#pragma unroll
        for (int g = 0; g < 4; ++g) {
            wa0[g] = wadd[(size_t)(t*2+0)*512 + 128*g + 16*w + li];
            wa1[g] = wadd[(size_t)(t*2+1)*512 + 128*g + 16*w + li];
        }
        const int sb = t & 1;
        const int j  = 16*w + li;
        const int jsh = 16*((j >> 3) & 3);
        const int jki = j >> 5;
        const int je  = j & 7;
#pragma unroll
        for (int mt = 0; mt < 2; ++mt) {
#pragma unroll
            for (int r = 0; r < 4; ++r) {
                int row = mt*16 + lk*4 + r;
                float ad0 = Sadd[sb][row][0], ad1 = Sadd[sb][row][1];
                float v0 = acc[mt][0][r] + ad0*wa0[0] + ad1*wa1[0];
                float v1 = acc[mt][1][r] + ad0*wa0[1] + ad1*wa1[1];
                float v2 = acc[mt][2][r] + ad0*wa0[2] + ad1*wa1[2];
                float v3 = acc[mt][3][r] + ad0*wa0[3] + ad1*wa1[3];
                float iv = sigm(v0);
                float fv = sigm(v1);
                float gv = tanh_fast(v2);
                float ov = sigm(v3);
                float cn = fv*c[mt][r] + iv*gv;
                c[mt][r] = cn;
                float hv = ov*tanh_fast(cn);
                unsigned short hs = f2bf(hv);
                int ln = (row & 15) + jsh;
                aP[AIDX(0, jki, mt, ln) + je] = (short)hs;
                aP[AIDX(1, jki, mt, ln) + je] = (short)f2bf(hv - bf2f(hs));
                if (t == TT-1) hbuf[(size_t)(R0+row)*128 + j] = hv;
            }
        }
        if (t < TT-1) {
            int row = tid >> 4, d0 = (tid & 15)*4;
            int R = R0 + row, g = R/10, p = R - 10*g;
            float4 f = *(const float4*)&emb[((size_t)(g*TT + (t+1))*PP + p)*64 + d0];
            int k0 = 128 + d0;
            int mt = row>>4, ln = (row&15) + 16*((k0>>3)&3), ki = k0>>5, e0 = k0&7;
            float v[4] = {f.x,f.y,f.z,f.w};
            short4v hi, lo;
#pragma unroll
            for (int e = 0; e < 4; ++e) {
                unsigned short hs = f2bf(v[e]);
                hi[e] = (short)hs;
                lo[e] = (short)f2bf(v[e] - bf2f(hs));
            }
            *(short4v*)&aP[AIDX(0,ki,mt,ln)+e0] = hi;
            *(short4v*)&aP[AIDX(1,ki,mt,ln)+e0] = lo;
            if (tid < 64) {
                int rw = tid >> 1, cc = tid & 1;
                int R2 = R0 + rw, g2 = R2/10, p2 = R2 - 10*g2;
                Sadd[sb^1][rw][cc] =
                    add_info[((size_t)(g2*MM + (t+1)/MM)*PP + p2)*2 + cc];
            }
        }
        __syncthreads();
    }
}

// ---------------------------------------------------------------------------
// Final projection: out = h_last @ Wf + bf
// ---------------------------------------------------------------------------
__global__ __launch_bounds__(256) void final_proj(
    const float* __restrict__ hbuf, const float* __restrict__ Wf,
    const float* __restrict__ bf, float* __restrict__ out)
{
    __shared__ float wl[128*32];
    __shared__ float hl[64][128];
    const int tid = threadIdx.x;
    const int row0 = blockIdx.x * 64;
    for (int i = tid; i < 4096; i += 256) wl[i] = Wf[i];
    for (int i = tid; i < 8192; i += 256) hl[i>>7][i&127] = hbuf[row0*128 + i];
    __syncthreads();
    const int e  = tid & 31;
    const int rg = tid >> 5;
    float b = bf[e];
    float acc[8];
#pragma unroll
    for (int r=0;r<8;++r) acc[r] = b;
    for (int k = 0; k < 128; ++k) {
        float ww = wl[k*32 + e];
#pragma unroll
        for (int r=0;r<8;++r) acc[r] += hl[rg*8+r][k]*ww;
    }
#pragma unroll
    for (int r=0;r<8;++r) out[(row0 + rg*8 + r)*32 + e] = acc[r];
}

// ---------------------------------------------------------------------------
extern "C" void kernel_launch(void* const* d_in, const int* in_sizes, int n_in,
                              void* d_out, int out_size, void* d_ws, size_t ws_size,
                              hipStream_t stream)
{
    const float* x0       = (const float*)d_in[0];
    const float* add_info = (const float*)d_in[1];
    const float* Wb_pos   = (const float*)d_in[2];
    const float* bb_pos   = (const float*)d_in[3];
    const float* Wb_neg   = (const float*)d_in[4];
    const float* bb_neg   = (const float*)d_in[5];
    const float* Wd_pos   = (const float*)d_in[6];
    const float* bd_pos   = (const float*)d_in[7];
    const float* Wd_neg   = (const float*)d_in[8];
    const float* bd_neg   = (const float*)d_in[9];
    const float* W_ih     = (const float*)d_in[10];
    const float* W_hh     = (const float*)d_in[11];
    const float* b_ih     = (const float*)d_in[12];
    const float* b_hh     = (const float*)d_in[13];
    const float* hx0      = (const float*)d_in[14];
    const float* cx0      = (const float*)d_in[15];
    const float* Wf       = (const float*)d_in[16];
    const float* bf       = (const float*)d_in[17];
    const int*   pos_src  = (const int*)d_in[18];
    const int*   pos_dst  = (const int*)d_in[19];
    const int*   neg_src  = (const int*)d_in[20];
    const int*   neg_dst  = (const int*)d_in[21];

    float* ws    = (float*)d_ws;
    float* emb   = ws;                        // 8,192,000 f32
    float* hbuf  = emb   + 8192000;           //   655,360 f32
    float* bsumw = hbuf  + 655360;            //    12,800 f32
    float* waddw = bsumw + 12800;             //    25,600 f32
    short* wBw   = (short*)(waddw + 25600);   // 4,915,200 bf16-bits (~45.4 MiB total)

    hipLaunchKernelGGL(prep_kernel, dim3(2048), dim3(256), 0, stream,
                       W_ih, W_hh, b_ih, b_hh, wBw, waddw, bsumw);
    hipLaunchKernelGGL(graph_kernel, dim3(NGRAPH), dim3(64), 0, stream,
                       x0, Wb_pos, bb_pos, Wb_neg, bb_neg,
                       Wd_pos, bd_pos, Wd_neg, bd_neg,
                       pos_src, pos_dst, neg_src, neg_dst, emb);
    hipLaunchKernelGGL(lstm_mfma, dim3(160), dim3(512), 0, stream,
                       emb, add_info, wBw, waddw, bsumw, hx0, cx0, hbuf);
    hipLaunchKernelGGL(final_proj, dim3(80), dim3(256), 0, stream,
                       hbuf, Wf, bf, (float*)d_out);
}